// Round 1
// baseline (77.092 us; speedup 1.0000x reference)
//
#include <hip/hip_runtime.h>
#include <math.h>

// DiscreteBayesianFlow: probs = softmax(beta*(K*onehot(x)-1) + sqrt(beta)*(noise @ L0^T))
// L0 = chol((K+0.001)I - 11^T) has closed form (diag-plus-rank-one):
//   t_j = d/(j-d), a_j = sqrt(d+t_j) (diag), b_j = t_j/a_j (below-diag), d = K+0.001
// => (noise @ L0^T)_j = prefsum_{k<j}(noise_k*b_k) + noise_j*a_j  -- O(K) scan per row.

#define NCLS 256

__global__ __launch_bounds__(256) void dbf_kernel(
    const int* __restrict__ data,
    const float* __restrict__ t,
    const float4* __restrict__ noise4,
    float4* __restrict__ out4,
    int n_rows)
{
    __shared__ float4 s_b4[64];
    __shared__ float4 s_a4[64];
    {
        const int k = threadIdx.x;            // one column per thread
        const double d = 256.001;
        const double tk = d / ((double)k - d);   // negative
        const double ak = sqrt(d + tk);
        ((float*)s_a4)[k] = (float)ak;
        ((float*)s_b4)[k] = (float)(tk / ak);
    }
    __syncthreads();

    const int lane = threadIdx.x & 63;
    const int wave = threadIdx.x >> 6;
    const int row  = blockIdx.x * 4 + wave;
    if (row >= n_rows) return;

    const float4 nz = noise4[(size_t)row * 64 + lane];
    const float4 bv = s_b4[lane];
    const float4 av = s_a4[lane];

    // weighted terms for the prefix sum
    const float w0 = nz.x * bv.x;
    const float w1 = nz.y * bv.y;
    const float w2 = nz.z * bv.z;
    const float w3 = nz.w * bv.w;
    const float local = w0 + w1 + w2 + w3;

    // inclusive wave scan over 64 lanes -> exclusive base
    float v = local;
    #pragma unroll
    for (int off = 1; off < 64; off <<= 1) {
        float n = __shfl_up(v, off, 64);
        if (lane >= off) v += n;
    }
    const float base = v - local;

    // scalars for this row
    const float tt = t[row];
    float sb = fminf(tt, 1.0f - 1e-6f);       // * MAX_SQRT_BETA (=1)
    const bool lo = sb < 1e-10f;
    sb = fmaxf(sb, 1e-10f);
    const float beta = sb * sb;
    const int  x = data[row];

    const int j0 = lane * 4;
    const float dot0 = base + nz.x * av.x;
    const float dot1 = base + w0 + nz.y * av.y;
    const float dot2 = base + w0 + w1 + nz.z * av.z;
    const float dot3 = base + w0 + w1 + w2 + nz.w * av.w;

    float l0 = beta * (256.0f * (float)(j0 + 0 == x) - 1.0f) + sb * dot0;
    float l1 = beta * (256.0f * (float)(j0 + 1 == x) - 1.0f) + sb * dot1;
    float l2 = beta * (256.0f * (float)(j0 + 2 == x) - 1.0f) + sb * dot2;
    float l3 = beta * (256.0f * (float)(j0 + 3 == x) - 1.0f) + sb * dot3;

    // softmax over 256 (wave reduction)
    float m = fmaxf(fmaxf(l0, l1), fmaxf(l2, l3));
    #pragma unroll
    for (int off = 32; off > 0; off >>= 1)
        m = fmaxf(m, __shfl_xor(m, off, 64));

    const float e0 = expf(l0 - m);
    const float e1 = expf(l1 - m);
    const float e2 = expf(l2 - m);
    const float e3 = expf(l3 - m);
    float s = e0 + e1 + e2 + e3;
    #pragma unroll
    for (int off = 32; off > 0; off >>= 1)
        s += __shfl_xor(s, off, 64);
    const float inv = 1.0f / s;

    float4 o;
    if (lo) {
        const float u = 1.0f / 256.0f;
        o.x = u; o.y = u; o.z = u; o.w = u;
    } else {
        o.x = e0 * inv; o.y = e1 * inv; o.z = e2 * inv; o.w = e3 * inv;
    }
    out4[(size_t)row * 64 + lane] = o;
}

extern "C" void kernel_launch(void* const* d_in, const int* in_sizes, int n_in,
                              void* d_out, int out_size, void* d_ws, size_t ws_size,
                              hipStream_t stream) {
    const int*    data   = (const int*)d_in[0];
    const float*  t      = (const float*)d_in[1];
    const float4* noise4 = (const float4*)d_in[2];
    float4*       out4   = (float4*)d_out;

    const int n_rows = in_sizes[1];           // B*S
    const int blocks = (n_rows + 3) / 4;      // 4 rows (waves) per block
    dbf_kernel<<<blocks, 256, 0, stream>>>(data, t, noise4, out4, n_rows);
}

// Round 2
// 76.645 us; speedup vs baseline: 1.0058x; 1.0058x over previous
//
#include <hip/hip_runtime.h>
#include <math.h>

// DiscreteBayesianFlow: probs = softmax(beta*(K*onehot(x)-1) + sqrt(beta)*(noise @ L0^T))
// L0 = chol((K+0.001)I - 11^T), diag-plus-rank-one closed form:
//   t_j = d/(j-d), a_j = sqrt(d+t_j), b_j = t_j/a_j, d = K+0.001
// => (noise @ L0^T)_j = prefix_{k<j}(noise_k*b_k) + noise_j*a_j  -- O(K) wave scan.
// All cross-lane ops via GCN DPP (pure VALU, no LDS pipe / lgkmcnt latency).

#define ROWS_PER_WAVE 2

template<int CTRL, int RM>
__device__ __forceinline__ float dpp_f(float oldv, float x) {
    return __int_as_float(__builtin_amdgcn_update_dpp(
        __float_as_int(oldv), __float_as_int(x), CTRL, RM, 0xF, false));
}

// inclusive prefix-sum across the 64-lane wave (row_shr tree + row_bcast)
__device__ __forceinline__ float wave_iscan_add(float x) {
    x += dpp_f<0x111, 0xF>(0.0f, x);   // row_shr:1
    x += dpp_f<0x112, 0xF>(0.0f, x);   // row_shr:2
    x += dpp_f<0x114, 0xF>(0.0f, x);   // row_shr:4
    x += dpp_f<0x118, 0xF>(0.0f, x);   // row_shr:8
    x += dpp_f<0x142, 0xA>(0.0f, x);   // row_bcast:15 -> rows 1,3
    x += dpp_f<0x143, 0xC>(0.0f, x);   // row_bcast:31 -> rows 2,3
    return x;
}

__device__ __forceinline__ float wave_bcast_sum(float x) {
    x = wave_iscan_add(x);
    return __int_as_float(__builtin_amdgcn_readlane(__float_as_int(x), 63));
}

__device__ __forceinline__ float wave_bcast_max(float x) {
    // old = own value (identity for max); invalid/masked lanes contribute self
    x = fmaxf(x, dpp_f<0x111, 0xF>(x, x));
    x = fmaxf(x, dpp_f<0x112, 0xF>(x, x));
    x = fmaxf(x, dpp_f<0x114, 0xF>(x, x));
    x = fmaxf(x, dpp_f<0x118, 0xF>(x, x));
    x = fmaxf(x, dpp_f<0x142, 0xA>(x, x));
    x = fmaxf(x, dpp_f<0x143, 0xC>(x, x));
    return __int_as_float(__builtin_amdgcn_readlane(__float_as_int(x), 63));
}

__global__ __launch_bounds__(256) void dbf_kernel(
    const int* __restrict__ data,
    const float* __restrict__ t,
    const float4* __restrict__ noise4,
    float4* __restrict__ out4,
    int n_rows)
{
    const int lane = threadIdx.x & 63;
    const int wave = threadIdx.x >> 6;
    const int row0 = (blockIdx.x * 4 + wave) * ROWS_PER_WAVE;
    if (row0 >= n_rows) return;

    // closed-form Cholesky coefficients for this lane's 4 classes (once, registers)
    float av[4], bv[4];
    #pragma unroll
    for (int i = 0; i < 4; ++i) {
        const double d = 256.001;
        const double tk = d / ((double)(lane * 4 + i) - d);
        const double a = sqrt(d + tk);
        av[i] = (float)a;
        bv[i] = (float)(tk / a);
    }

    // issue all global loads up front (ROWS_PER_WAVE independent chains)
    float4 nz[ROWS_PER_WAVE];
    float  tt[ROWS_PER_WAVE];
    int    xx[ROWS_PER_WAVE];
    bool   ok[ROWS_PER_WAVE];
    #pragma unroll
    for (int r = 0; r < ROWS_PER_WAVE; ++r) {
        const int row = row0 + r;
        ok[r] = (row < n_rows);
        const int rr = ok[r] ? row : 0;
        nz[r] = noise4[(size_t)rr * 64 + lane];
        tt[r] = t[rr];
        xx[r] = data[rr];
    }

    #pragma unroll
    for (int r = 0; r < ROWS_PER_WAVE; ++r) {
        if (!ok[r]) continue;
        const float w0 = nz[r].x * bv[0];
        const float w1 = nz[r].y * bv[1];
        const float w2 = nz[r].z * bv[2];
        const float w3 = nz[r].w * bv[3];
        const float local = w0 + w1 + w2 + w3;
        const float base  = wave_iscan_add(local) - local;

        float sb = fminf(tt[r], 1.0f - 1e-6f);   // * MAX_SQRT_BETA (=1)
        const bool lo = sb < 1e-10f;
        sb = fmaxf(sb, 1e-10f);
        const float beta = sb * sb;
        const int x = xx[r];
        const int j0 = lane * 4;

        float l0 = beta * (256.0f * (float)(j0 + 0 == x) - 1.0f) + sb * (base + nz[r].x * av[0]);
        float l1 = beta * (256.0f * (float)(j0 + 1 == x) - 1.0f) + sb * (base + w0 + nz[r].y * av[1]);
        float l2 = beta * (256.0f * (float)(j0 + 2 == x) - 1.0f) + sb * (base + w0 + w1 + nz[r].z * av[2]);
        float l3 = beta * (256.0f * (float)(j0 + 3 == x) - 1.0f) + sb * (base + w0 + w1 + w2 + nz[r].w * av[3]);

        const float m = wave_bcast_max(fmaxf(fmaxf(l0, l1), fmaxf(l2, l3)));

        const float LOG2E = 1.4426950408889634f;
        const float e0 = exp2f((l0 - m) * LOG2E);
        const float e1 = exp2f((l1 - m) * LOG2E);
        const float e2 = exp2f((l2 - m) * LOG2E);
        const float e3 = exp2f((l3 - m) * LOG2E);
        const float s = wave_bcast_sum(e0 + e1 + e2 + e3);
        const float inv = 1.0f / s;

        float4 o;
        if (lo) {
            const float u = 1.0f / 256.0f;
            o.x = u; o.y = u; o.z = u; o.w = u;
        } else {
            o.x = e0 * inv; o.y = e1 * inv; o.z = e2 * inv; o.w = e3 * inv;
        }
        out4[(size_t)(row0 + r) * 64 + lane] = o;
    }
}

extern "C" void kernel_launch(void* const* d_in, const int* in_sizes, int n_in,
                              void* d_out, int out_size, void* d_ws, size_t ws_size,
                              hipStream_t stream) {
    const int*    data   = (const int*)d_in[0];
    const float*  t      = (const float*)d_in[1];
    const float4* noise4 = (const float4*)d_in[2];
    float4*       out4   = (float4*)d_out;

    const int n_rows = in_sizes[1];                       // B*S
    const int rows_per_block = 4 * ROWS_PER_WAVE;         // 4 waves/block
    const int blocks = (n_rows + rows_per_block - 1) / rows_per_block;
    dbf_kernel<<<blocks, 256, 0, stream>>>(data, t, noise4, out4, n_rows);
}